// Round 11
// baseline (3090.361 us; speedup 1.0000x reference)
//
#include <hip/hip_runtime.h>
#include <hip/hip_bf16.h>

#define HH 51
#define TPB 256     // 4 waves; P1: 2 batches/wave; P2: waves 0-2 = one matrix each
#define BPB 8       // grid 256 = 1 block/CU; M=8 rows per MFMA
#define GMS 10      // gbuf row stride (floats): even -> paired float2 reads

typedef _Float16 half8 __attribute__((ext_vector_type(8)));
typedef float f4 __attribute__((ext_vector_type(4)));

__device__ __forceinline__ float bf2f(unsigned short u) {
    return __uint_as_float(((unsigned)u) << 16);
}
__device__ __forceinline__ float loadf(const void* p, size_t i, bool bf) {
    return bf ? bf2f(((const unsigned short*)p)[i]) : ((const float*)p)[i];
}
__device__ __forceinline__ void storef(void* p, size_t i, float v, bool bf) {
    if (bf) ((__hip_bfloat16*)p)[i] = __float2bfloat16(v);
    else    ((float*)p)[i] = v;
}
__device__ __forceinline__ float sigm(float v) {
    float e = __expf(-fabsf(v));
    float s = 1.0f / (1.0f + e);
    return (v >= 0.0f) ? s : 1.0f - s;
}
__device__ __forceinline__ float tanh_fast(float v) {
    float e = __expf(-2.0f * fabsf(v));
    float t = (1.0f - e) / (1.0f + e);
    return (v >= 0.0f) ? t : -t;
}
__device__ __forceinline__ f4 MF(half8 a, half8 b, f4 c) {
    return __builtin_amdgcn_mfma_f32_16x16x32_f16(a, b, c, 0, 0, 0);
}
// wave64 sum via DPP (verified rounds 5-10), result uniform across lanes
__device__ __forceinline__ float wave_sum(float x) {
    float s = x, t;
    t = __builtin_bit_cast(float, __builtin_amdgcn_update_dpp(0, __builtin_bit_cast(int, s), 0x111, 0xf, 0xf, true)); s += t;
    t = __builtin_bit_cast(float, __builtin_amdgcn_update_dpp(0, __builtin_bit_cast(int, s), 0x112, 0xf, 0xf, true)); s += t;
    t = __builtin_bit_cast(float, __builtin_amdgcn_update_dpp(0, __builtin_bit_cast(int, s), 0x114, 0xf, 0xf, true)); s += t;
    t = __builtin_bit_cast(float, __builtin_amdgcn_update_dpp(0, __builtin_bit_cast(int, s), 0x118, 0xf, 0xf, true)); s += t;
    t = __builtin_bit_cast(float, __builtin_amdgcn_update_dpp(0, __builtin_bit_cast(int, s), 0x142, 0xa, 0xf, true)); s += t;
    t = __builtin_bit_cast(float, __builtin_amdgcn_update_dpp(0, __builtin_bit_cast(int, s), 0x143, 0xc, 0xf, true)); s += t;
    return __builtin_bit_cast(float, __builtin_amdgcn_readlane(__builtin_bit_cast(int, s), 63));
}

__global__ __launch_bounds__(TPB, 1) void gru_kernel(
    const void* __restrict__ xg,
    const void* __restrict__ wih1, const void* __restrict__ whh1,
    const void* __restrict__ bih1, const void* __restrict__ bhh1,
    const void* __restrict__ wih2, const void* __restrict__ whh2,
    const void* __restrict__ bih2, const void* __restrict__ bhh2,
    const void* __restrict__ wlin, const void* __restrict__ blin_p,
    void* __restrict__ dout, int T, int TF)
{
    __shared__ __align__(16) _Float16 stg[160 * 64];          // 20480 B
    __shared__ __align__(16) float    gbuf[3 * 160 * GMS];    // 19200 B
    __shared__ __align__(16) _Float16 h1hi[16 * 72];          // rows: batch(8)+zero
    __shared__ __align__(16) _Float16 h1lo[16 * 72];
    __shared__ __align__(16) _Float16 h2hi[16 * 72];
    __shared__ __align__(16) _Float16 h2lo[16 * 72];
    __shared__ float obufL[BPB * 36];

    const int tid = threadIdx.x, w = tid >> 6, lane = tid & 63;
    const int n16 = lane & 15, quad = lane >> 4;
    const bool li = lane < HH;
    const int il = li ? lane : HH - 1;
    const int bg0 = blockIdx.x * BPB;
    const int bA = 2 * w, bB = 2 * w + 1;      // local batches of this wave

    // runtime dtype detection (fp32 vs bf16), uniform
    bool isbf;
    {
        const unsigned short* u = (const unsigned short*)whh1;
        int ok = 1;
#pragma unroll
        for (int k = 0; k < 16; ++k) {
            unsigned e = (u[2 * k] >> 7) & 0xFF;
            ok &= (e >= 100 && e <= 125) ? 1 : 0;
        }
        isbf = (ok != 0);
    }

    // ---- stage matrices (f16, bias folded at k=52); wave w<3 snapshots matrix w ----
    half8 W[10][2];
#pragma unroll 1
    for (int mt = 0; mt < 3; ++mt) {
        const void* wm = (mt == 0) ? whh1 : (mt == 1) ? whh2 : wih2;
        for (int e = tid; e < 160 * 64; e += TPB) {
            int g = e >> 6, k = e & 63;
            float v = 0.0f;
            if (g < 3 * HH) {
                if (k < HH) v = loadf(wm, (size_t)g * HH + k, isbf);
                else if (k == 52) {
                    if (mt == 0)      v = loadf(bhh1, g, isbf) + ((g < 2 * HH) ? loadf(bih1, g, isbf) : 0.0f);
                    else if (mt == 1) v = loadf(bhh2, g, isbf);
                    else              v = loadf(bih2, g, isbf);
                }
            }
            stg[e] = (_Float16)v;
        }
        __syncthreads();
        if (w == mt) {
#pragma unroll
            for (int tl = 0; tl < 10; ++tl) {
                W[tl][0] = *(const half8*)(stg + (size_t)(16 * tl + n16) * 64 + quad * 8);
                W[tl][1] = *(const half8*)(stg + (size_t)(16 * tl + n16) * 64 + 32 + quad * 8);
            }
        }
        __syncthreads();
    }

    // ---- init runtime LDS ----
    for (int e = tid; e < 1152; e += TPB) { h1hi[e] = (_Float16)0; h1lo[e] = (_Float16)0;
                                            h2hi[e] = (_Float16)0; h2lo[e] = (_Float16)0; }
    for (int e = tid; e < 3 * 160 * GMS; e += TPB) gbuf[e] = 0.0f;

    // elementwise constants (lane = hidden unit, shared by both batches)
    float wr1 = 0, wz1 = 0, wn1 = 0, bn1 = 0, wl = 0;
    if (li) {
        wr1 = loadf(wih1, il, isbf);          wz1 = loadf(wih1, HH + il, isbf);
        wn1 = loadf(wih1, 2 * HH + il, isbf); bn1 = loadf(bih1, 2 * HH + il, isbf);
        wl  = loadf(wlin, il, isbf);
    }
    const float blv = loadf(blin_p, 0, isbf);

    // x prefetch: lane l = (batch lane&1, step l>>1), 32 steps per reload
    float xreg = 0.0f;
    { int src = lane >> 1;
      if (src < T) xreg = loadf(xg, (size_t)(bg0 + 2 * w + (lane & 1)) * T + src, isbf); }
    __syncthreads();
    if (tid < BPB) { h1hi[tid * 72 + 52] = (_Float16)1.0f; h2hi[tid * 72 + 52] = (_Float16)1.0f; }
    __syncthreads();

    // ---- prologue: wave0 computes gh1(0) from bias-slot h1 ----
    if (w == 0) {
        half8 Ah0 = *(const half8*)(h1hi + n16 * 72 + quad * 8);
        half8 Ah1 = *(const half8*)(h1hi + n16 * 72 + 32 + quad * 8);
        half8 Al0 = *(const half8*)(h1lo + n16 * 72 + quad * 8);
        half8 Al1 = *(const half8*)(h1lo + n16 * 72 + 32 + quad * 8);
#pragma unroll
        for (int tl = 0; tl < 10; ++tl) {
            f4 acc = {0.f, 0.f, 0.f, 0.f};
            acc = MF(Ah0, W[tl][0], acc); acc = MF(Ah1, W[tl][1], acc);
            acc = MF(Al0, W[tl][0], acc); acc = MF(Al1, W[tl][1], acc);
            if (quad < 2) *(f4*)(gbuf + (16 * tl + n16) * GMS + quad * 4) = acc;
        }
    }
    __syncthreads();

    const float2* gb2 = (const float2*)gbuf;   // paired (bA,bB) column reads
    const int base1 = 160 * GMS, base2 = 320 * GMS;
    float h1pA = 0, h1pB = 0, h2pA = 0, h2pB = 0;

    for (int t = 0; t < TF; ++t) {
        // ======== P1: elementwise, 2 batches per wave ========
        float2 g1r = gb2[(il * GMS + bA) >> 1];
        float2 g1z = gb2[((HH + il) * GMS + bA) >> 1];
        float2 g1n = gb2[((2 * HH + il) * GMS + bA) >> 1];
        float outA = 0.0f, outB = 0.0f;
        if (t > 0) {   // e2(t-1) for both batches
            float2 ghr = gb2[(base1 + il * GMS + bA) >> 1];
            float2 ghz = gb2[(base1 + (HH + il) * GMS + bA) >> 1];
            float2 ghn = gb2[(base1 + (2 * HH + il) * GMS + bA) >> 1];
            float2 gir = gb2[(base2 + il * GMS + bA) >> 1];
            float2 giz = gb2[(base2 + (HH + il) * GMS + bA) >> 1];
            float2 gin = gb2[(base2 + (2 * HH + il) * GMS + bA) >> 1];
            float pA = 0.f, pB = 0.f;
            {
                float r2 = sigm(gir.x + ghr.x), z2 = sigm(giz.x + ghz.x);
                float n2 = tanh_fast(gin.x + r2 * ghn.x);
                float h = n2 + z2 * (h2pA - n2); h2pA = h;
                if (li) {
                    _Float16 hi = (_Float16)h;
                    h2hi[bA * 72 + il] = hi; h2lo[bA * 72 + il] = (_Float16)(h - (float)hi);
                    pA = h * wl;
                }
            }
            {
                float r2 = sigm(gir.y + ghr.y), z2 = sigm(giz.y + ghz.y);
                float n2 = tanh_fast(gin.y + r2 * ghn.y);
                float h = n2 + z2 * (h2pB - n2); h2pB = h;
                if (li) {
                    _Float16 hi = (_Float16)h;
                    h2hi[bB * 72 + il] = hi; h2lo[bB * 72 + il] = (_Float16)(h - (float)hi);
                    pB = h * wl;
                }
            }
            outA = wave_sum(pA) + blv;
            outB = wave_sum(pB) + blv;
            int slp = (t - 1) & 31;
            if (lane == 0) { obufL[bA * 36 + slp] = outA; obufL[bB * 36 + slp] = outB; }
        }
        float xvA, xvB;
        if (t < T) {
            int sl5 = t & 31;
            xvA = __builtin_bit_cast(float, __builtin_amdgcn_readlane(__builtin_bit_cast(int, xreg), 2 * sl5));
            xvB = __builtin_bit_cast(float, __builtin_amdgcn_readlane(__builtin_bit_cast(int, xreg), 2 * sl5 + 1));
        } else { xvA = outA; xvB = outB; }
        {   // e1(t) batch A
            float r = sigm(fmaf(xvA, wr1, g1r.x));
            float z = sigm(fmaf(xvA, wz1, g1z.x));
            float n = tanh_fast(fmaf(xvA, wn1, bn1) + r * g1n.x);
            float h = n + z * (h1pA - n); h1pA = h;
            if (li) {
                _Float16 hi = (_Float16)h;
                h1hi[bA * 72 + il] = hi; h1lo[bA * 72 + il] = (_Float16)(h - (float)hi);
            }
        }
        {   // e1(t) batch B
            float r = sigm(fmaf(xvB, wr1, g1r.y));
            float z = sigm(fmaf(xvB, wz1, g1z.y));
            float n = tanh_fast(fmaf(xvB, wn1, bn1) + r * g1n.y);
            float h = n + z * (h1pB - n); h1pB = h;
            if (li) {
                _Float16 hi = (_Float16)h;
                h1hi[bB * 72 + il] = hi; h1lo[bB * 72 + il] = (_Float16)(h - (float)hi);
            }
        }
        __syncthreads();

        // ======== P2: waves 0-2 matmul (one matrix each); wave 3 flush ========
        if (w < 3) {
            const _Float16* ah = (w == 1) ? h2hi : h1hi;
            const _Float16* al = (w == 1) ? h2lo : h1lo;
            half8 Ah0 = *(const half8*)(ah + n16 * 72 + quad * 8);
            half8 Ah1 = *(const half8*)(ah + n16 * 72 + 32 + quad * 8);
            half8 Al0 = *(const half8*)(al + n16 * 72 + quad * 8);
            half8 Al1 = *(const half8*)(al + n16 * 72 + 32 + quad * 8);
            float* dst = gbuf + w * 160 * GMS;
#pragma unroll
            for (int tl = 0; tl < 10; ++tl) {
                f4 acc = {0.f, 0.f, 0.f, 0.f};
                acc = MF(Ah0, W[tl][0], acc); acc = MF(Ah1, W[tl][1], acc);
                acc = MF(Al0, W[tl][0], acc); acc = MF(Al1, W[tl][1], acc);
                if (quad < 2) *(f4*)(dst + (16 * tl + n16) * GMS + quad * 4) = acc;
            }
        } else if ((t & 31) == 0 && t > 0) {
            for (int e = lane; e < BPB * 32; e += 64) {
                int b = e >> 5, tt = e & 31;
                storef(dout, (size_t)(bg0 + b) * TF + (t - 32) + tt, obufL[b * 36 + tt], isbf);
            }
        }
        if ((t & 31) == 31 && (t + 1) < T) {   // x reload for [t+1, t+32]
            int src = t + 1 + (lane >> 1);
            xreg = (src < T) ? loadf(xg, (size_t)(bg0 + 2 * w + (lane & 1)) * T + src, isbf) : 0.0f;
        }
        __syncthreads();
    }

    // ---- epilogue: e2(TF-1) for both batches + tail flush ----
    {
        float2 ghr = gb2[(base1 + il * GMS + bA) >> 1];
        float2 ghz = gb2[(base1 + (HH + il) * GMS + bA) >> 1];
        float2 ghn = gb2[(base1 + (2 * HH + il) * GMS + bA) >> 1];
        float2 gir = gb2[(base2 + il * GMS + bA) >> 1];
        float2 giz = gb2[(base2 + (HH + il) * GMS + bA) >> 1];
        float2 gin = gb2[(base2 + (2 * HH + il) * GMS + bA) >> 1];
        float pA = 0.f, pB = 0.f;
        {
            float r2 = sigm(gir.x + ghr.x), z2 = sigm(giz.x + ghz.x);
            float n2 = tanh_fast(gin.x + r2 * ghn.x);
            float h = n2 + z2 * (h2pA - n2);
            if (li) pA = h * wl;
        }
        {
            float r2 = sigm(gir.y + ghr.y), z2 = sigm(giz.y + ghz.y);
            float n2 = tanh_fast(gin.y + r2 * ghn.y);
            float h = n2 + z2 * (h2pB - n2);
            if (li) pB = h * wl;
        }
        float outA = wave_sum(pA) + blv;
        float outB = wave_sum(pB) + blv;
        int slp = (TF - 1) & 31;
        if (lane == 0) { obufL[bA * 36 + slp] = outA; obufL[bB * 36 + slp] = outB; }
    }
    __syncthreads();
    {
        int base = (TF - 1) & ~31, rem = TF - base;
        if (tid < BPB * 32) {
            int b = tid >> 5, tt = tid & 31;
            if (tt < rem)
                storef(dout, (size_t)(bg0 + b) * TF + base + tt, obufL[b * 36 + tt], isbf);
        }
    }
}

extern "C" void kernel_launch(void* const* d_in, const int* in_sizes, int n_in,
                              void* d_out, int out_size, void* d_ws, size_t ws_size,
                              hipStream_t stream) {
    const int B = 2048;
    const int T = in_sizes[0] / B;   // 1000
    const int TF = out_size / B;     // 2000
    gru_kernel<<<dim3(B / BPB), dim3(TPB), 0, stream>>>(
        d_in[0], d_in[1], d_in[2], d_in[3], d_in[4], d_in[5],
        d_in[6], d_in[7], d_in[8], d_in[9], d_in[10],
        d_out, T, TF);
}